// Round 10
// baseline (2375.963 us; speedup 1.0000x reference)
//
#include <hip/hip_runtime.h>
#include <math.h>

#define T_ALL 200
#define ROWB  1040                 // 1024 B h-row + 16 B pad (16B-aligned)
#define QUAD  (32 * ROWB)          // 33,280 B per h quadrant

typedef __attribute__((ext_vector_type(8)))  short v8s;
typedef __attribute__((ext_vector_type(16))) float v16f;

typedef __attribute__((address_space(1))) const unsigned int g_u32;
typedef __attribute__((address_space(3))) unsigned int l_u32;

// device-coherent global->LDS: aux=16 (sc1) reads the L3 coherence point,
// bypassing the possibly-stale local L2 (proven in prior sessions).
__device__ __forceinline__ void gl2lds16_coh(const void* g, void* l) {
    __builtin_amdgcn_global_load_lds((g_u32*)g, (l_u32*)l, 16, 0, 16);
}

__device__ __forceinline__ unsigned short f2bf(float f) {
    unsigned int u = __float_as_uint(f);
    u += 0x7FFF + ((u >> 16) & 1);          // round-to-nearest-even
    return (unsigned short)(u >> 16);
}
__device__ __forceinline__ float bf2f(unsigned short s) {
    return __uint_as_float(((unsigned int)s) << 16);
}
// hardware-exp transcendentals (v_exp_f32): ~1e-7 error, saturation-safe
__device__ __forceinline__ float sigf(float x)  { return 1.0f / (1.0f + __expf(-x)); }
__device__ __forceinline__ float tanhf_hw(float x) {
    return 1.0f - 2.0f / (__expf(2.0f * x) + 1.0f);   // e=inf -> 1; e=0 -> -1
}

// ---- ws layout (bytes) ----
#define A_FRAGS   6656ULL
#define A_HI_OFF  0ULL
#define A_LO_OFF  (A_FRAGS * 1024ULL)
#define X_HI_OFF  (2ULL * A_FRAGS * 1024ULL)
#define X_BYTES   (200ULL * 256 * 128 * 2)
#define X_LO_OFF  (X_HI_OFF + X_BYTES)
#define H_BYTES   (2ULL * 256 * 512 * 2)
#define HHI0_OFF  (X_LO_OFF + X_BYTES)
#define HLO0_OFF  (HHI0_OFF + H_BYTES)
#define HHI1_OFF  (HLO0_OFF + H_BYTES)
#define HLO1_OFF  (HHI1_OFF + H_BYTES)
#define B0PK_OFF  (HLO1_OFF + H_BYTES)
#define B1PK_OFF  (B0PK_OFF + 8192ULL)
#define ARR_OFF   (B1PK_OFF + 8192ULL)
#define ARR_BYTES (256ULL * 64)              // one 64B-spread arrive slot per block

// Pack W rows into MFMA 32x32x16 A-fragment order, bf16 hi/lo planes.
__global__ __launch_bounds__(64) void pack_w(
    const float* __restrict__ Wih0, const float* __restrict__ Whh0,
    const float* __restrict__ Wih1, const float* __restrict__ Whh1,
    unsigned short* __restrict__ Ahi, unsigned short* __restrict__ Alo)
{
    const int fi = blockIdx.x, lane = threadIdx.x;
    const float* W; int K, hg, c;
    if (fi < 512)       { W = Wih0; K = 128; hg = fi >> 3;          c = fi & 7;          }
    else if (fi < 2560) { W = Whh0; K = 512; hg = (fi - 512) >> 5;  c = (fi - 512) & 31; }
    else if (fi < 4608) { W = Wih1; K = 512; hg = (fi - 2560) >> 5; c = (fi - 2560) & 31;}
    else                { W = Whh1; K = 512; hg = (fi - 4608) >> 5; c = (fi - 4608) & 31;}
    const int m = lane & 31, half = lane >> 5;
    const int q = m & 3, hl = m >> 2;
    const int r = q * 512 + hg * 8 + hl;
    const int k0 = c * 16 + half * 8;
    const float* src = W + (size_t)r * K + k0;
    unsigned short* dh = Ahi + (size_t)fi * 512 + lane * 8;
    unsigned short* dl = Alo + (size_t)fi * 512 + lane * 8;
    #pragma unroll
    for (int j = 0; j < 8; ++j) {
        const float w = src[j];
        const unsigned short h = f2bf(w);
        dh[j] = h;
        dl[j] = f2bf(w - bf2f(h));
    }
}

// proposals [b][t][c] fp32 -> xHi/xLo [t][b][c] bf16
__global__ __launch_bounds__(256) void prep_x(const float* __restrict__ prop,
                                              unsigned short* __restrict__ xHi,
                                              unsigned short* __restrict__ xLo)
{
    const int t = blockIdx.x, b = threadIdx.x;
    const float* src = prop + ((size_t)b * 200 + t) * 128;
    unsigned short* dh = xHi + ((size_t)t * 256 + b) * 128;
    unsigned short* dl = xLo + ((size_t)t * 256 + b) * 128;
    #pragma unroll 4
    for (int c = 0; c < 128; ++c) {
        const float f = src[c];
        const unsigned short h = f2bf(f);
        dh[c] = h;
        dl[c] = f2bf(f - bf2f(h));
    }
}

// bias packs: bpk[hid] = float4 over gates (i,f,g,o)
__global__ __launch_bounds__(512) void pack_bias(
    const float* __restrict__ bih0, const float* __restrict__ bhh0,
    const float* __restrict__ bih1, const float* __restrict__ bhh1,
    float4* __restrict__ b0, float4* __restrict__ b1)
{
    const int hid = threadIdx.x;
    float4 u, v;
    u.x = bih0[hid] + bhh0[hid];
    u.y = bih0[512 + hid] + bhh0[512 + hid];
    u.z = bih0[1024 + hid] + bhh0[1024 + hid];
    u.w = bih0[1536 + hid] + bhh0[1536 + hid];
    v.x = bih1[hid] + bhh1[hid];
    v.y = bih1[512 + hid] + bhh1[512 + hid];
    v.z = bih1[1024 + hid] + bhh1[1024 + hid];
    v.w = bih1[1536 + hid] + bhh1[1536 + hid];
    b0[hid] = u; b1[hid] = v;
}

// PERSISTENT fused scan -- R9 base (verified 2297us, best).  Single change:
// weight prefetch deepened 2 -> 4 rows (c=0..3, hi+lo) for recurrent waves.
// Mechanism (validated R9): loads issued pre-barrier1 drain concurrently
// with the sc1 staging burst -- staging reads L3 while weights read L2, so
// part of region A's L2 stream moves into the otherwise-L2-idle staging
// window, and region A starts with 4 warm row-pairs.  +16 VGPR (~120, under
// the 128 allocator cap; FETCH_SIZE is the spill tripwire).  Tail/protocol/
// store layout byte-identical to R9.
__global__ __launch_bounds__(512) void lstm_scan(
    const unsigned short* __restrict__ Ahi, const unsigned short* __restrict__ Alo,
    const unsigned short* __restrict__ xHi, const unsigned short* __restrict__ xLo,
    unsigned short* __restrict__ hHi0, unsigned short* __restrict__ hLo0,
    unsigned short* __restrict__ hHi1, unsigned short* __restrict__ hLo1,
    const float4* __restrict__ b0pk, const float4* __restrict__ b1pk,
    int* __restrict__ arr)
{
    __shared__ __align__(16) unsigned char dbuf[4 * QUAD];       // 133,120 B
    __shared__ float xch[2][2][32][32];                          //  16,384 B
    __shared__ __align__(16) unsigned short hst[2][2][32][16];   //   4,096 B

    const int tid  = threadIdx.x;
    const int wv   = tid >> 6, lane = tid & 63;
    const int mv   = wv >> 1, hgi = wv & 1;
    const int f    = blockIdx.x;                   // 0..255
    const int hgp  = (f & 7) * 4 + ((f >> 3) & 3); // 4 hg-pairs per XCD
    const int bt   = f >> 5;                       // batch tile 0..7 = sync group
    const int hg   = hgp * 2 + hgi;                // hid group 0..63
    const int ml   = lane & 31, half = lane >> 5;
    const int gslot = f & 31;                      // our slot within the group

    int fbase;
    if (mv == 0)      fbase = hg * 8;
    else if (mv == 1) fbase = 512 + hg * 32;
    else if (mv == 2) fbase = 2560 + hg * 32;
    else              fbase = 4608 + hg * 32;

    float4 bs[4];
    #pragma unroll
    for (int rq = 0; rq < 4; ++rq) {
        const int hid = hg * 8 + 2 * rq + half;
        bs[rq] = (mv == 1) ? b0pk[hid] : (mv == 3) ? b1pk[hid]
                                       : make_float4(0.f, 0.f, 0.f, 0.f);
    }
    float creg[4] = {0.f, 0.f, 0.f, 0.f};

    for (int t = 0; t <= T_ALL; ++t) {
        const int rs0 = (t + 1) & 1;   // h0[t-1] slot
        const int rs1 = t & 1;         // h1[t-2] slot
        const unsigned short* srcq[4] = {
            hHi0 + ((size_t)rs0 * 256 + bt * 32) * 512,
            hLo0 + ((size_t)rs0 * 256 + bt * 32) * 512,
            hHi1 + ((size_t)rs1 * 256 + bt * 32) * 512,
            hLo1 + ((size_t)rs1 * 256 + bt * 32) * 512 };

        // ---- single staging burst: 128 rows (4 quadrants x 32 batches) ----
        #pragma unroll
        for (int j = 0; j < 16; ++j) {
            const int row = wv * 16 + j;
            const int q = row >> 5, r = row & 31;
            gl2lds16_coh(srcq[q] + (size_t)r * 512 + lane * 8,
                         &dbuf[q * QUAD + r * ROWB]);
        }

        // recurrent waves: prefetch weight rows c=0..3 (drain with staging;
        // L2 path runs concurrently with the sc1/L3 staging burst)
        v8s pfh[4], pfl[4];
        if (mv >= 1) {
            #pragma unroll
            for (int c = 0; c < 4; ++c) {
                pfh[c] = *(const v8s*)(Ahi + ((size_t)(fbase + c)) * 512 + lane * 8);
                pfl[c] = *(const v8s*)(Alo + ((size_t)(fbase + c)) * 512 + lane * 8);
            }
        }

        v16f A0;
        #pragma unroll
        for (int i = 0; i < 16; ++i) A0[i] = 0.f;

        // mv0: x-matvec (plain loads, independent of dbuf) before the drain
        if (mv == 0 && t < T_ALL) {
            const unsigned short* xh = xHi + ((size_t)t * 256 + bt * 32 + ml) * 128 + half * 8;
            const unsigned short* xl = xLo + ((size_t)t * 256 + bt * 32 + ml) * 128 + half * 8;
            #pragma unroll
            for (int c = 0; c < 8; ++c) {
                const v8s ah = *(const v8s*)(Ahi + ((size_t)(fbase + c)) * 512 + lane * 8);
                const v8s al = *(const v8s*)(Alo + ((size_t)(fbase + c)) * 512 + lane * 8);
                const v8s bh = *(const v8s*)(xh + c * 16);
                const v8s bl = *(const v8s*)(xl + c * 16);
                A0 = __builtin_amdgcn_mfma_f32_32x32x16_bf16(ah, bh, A0, 0, 0, 0);
                A0 = __builtin_amdgcn_mfma_f32_32x32x16_bf16(al, bh, A0, 0, 0, 0);
                A0 = __builtin_amdgcn_mfma_f32_32x32x16_bf16(ah, bl, A0, 0, 0, 0);
            }
            #pragma unroll
            for (int r = 0; r < 16; ++r)
                xch[0][hgi][(r & 3) + 8 * (r >> 2) + 4 * half][ml] = A0[r];
            #pragma unroll
            for (int i = 0; i < 16; ++i) A0[i] = 0.f;
        }
        __syncthreads();   // barrier1: staging + prefetch drained, xch[0] published

        // wave 0 idle window: bounded pre-poll (byte-identical to R5/R9)
        bool preOK = false;
        if (wv == 0 && t < T_ALL) {
            #pragma unroll 1
            for (int it = 0; it < 4 && !preOK; ++it) {
                int v = 0x7FFFFFFF;
                if (lane < 32)
                    v = __hip_atomic_load(arr + ((size_t)bt * 32 + lane) * 16,
                                          __ATOMIC_RELAXED, __HIP_MEMORY_SCOPE_AGENT);
                preOK = __all(lane >= 32 || lane == gslot || v >= t + 1);
                if (!preOK) __builtin_amdgcn_s_sleep(1);
            }
        }

        // ---- recurrent matvecs from LDS (h0 for mv1/mv2, h1 for mv3) ----
        const bool a12 = (mv == 1) ? (t >= 1 && t < T_ALL)
                       : (mv == 2) ? (t >= 1) : false;
        const bool a3  = (mv == 3) && (t >= 2);
        if (a12 || a3) {
            const unsigned char* qhi = dbuf + (mv == 3 ? 2 : 0) * QUAD;
            const unsigned char* qlo = qhi + QUAD;
            // c = 0..3 peeled: weights already in registers (prefetched)
            #pragma unroll
            for (int c = 0; c < 4; ++c) {
                const v8s bh = *(const v8s*)(qhi + ml * ROWB + c * 32 + half * 16);
                const v8s bl = *(const v8s*)(qlo + ml * ROWB + c * 32 + half * 16);
                A0 = __builtin_amdgcn_mfma_f32_32x32x16_bf16(pfh[c], bh, A0, 0, 0, 0);
                A0 = __builtin_amdgcn_mfma_f32_32x32x16_bf16(pfl[c], bh, A0, 0, 0, 0);
                A0 = __builtin_amdgcn_mfma_f32_32x32x16_bf16(pfh[c], bl, A0, 0, 0, 0);
            }
            #pragma unroll 7
            for (int c = 4; c < 32; ++c) {
                const v8s ah = *(const v8s*)(Ahi + ((size_t)(fbase + c)) * 512 + lane * 8);
                const v8s al = *(const v8s*)(Alo + ((size_t)(fbase + c)) * 512 + lane * 8);
                const v8s bh = *(const v8s*)(qhi + ml * ROWB + c * 32 + half * 16);
                const v8s bl = *(const v8s*)(qlo + ml * ROWB + c * 32 + half * 16);
                A0 = __builtin_amdgcn_mfma_f32_32x32x16_bf16(ah, bh, A0, 0, 0, 0);
                A0 = __builtin_amdgcn_mfma_f32_32x32x16_bf16(al, bh, A0, 0, 0, 0);
                A0 = __builtin_amdgcn_mfma_f32_32x32x16_bf16(ah, bl, A0, 0, 0, 0);
            }
        }

        // mv1: full epilogue now (xch[0] already published)
        if (mv == 1 && t < T_ALL) {
            #pragma unroll
            for (int rq = 0; rq < 4; ++rq) {
                const int hl = 2 * rq + half;
                float a[4];
                #pragma unroll
                for (int j = 0; j < 4; ++j)
                    a[j] = A0[rq * 4 + j]
                         + xch[0][hgi][j + 8 * rq + 4 * half][ml]
                         + ((const float*)&bs[rq])[j];
                const float ig = sigf(a[0]), fg = sigf(a[1]);
                const float gg = tanhf_hw(a[2]), og = sigf(a[3]);
                creg[rq] = fg * creg[rq] + ig * gg;
                const float h = og * tanhf_hw(creg[rq]);
                const unsigned short hh = f2bf(h);
                hst[0][0][ml][hgi * 8 + hl] = hh;
                hst[0][1][ml][hgi * 8 + hl] = f2bf(h - bf2f(hh));
            }
        }
        if (mv == 2 && t >= 1) {
            #pragma unroll
            for (int r = 0; r < 16; ++r)
                xch[1][hgi][(r & 3) + 8 * (r >> 2) + 4 * half][ml] = A0[r];
        }
        __syncthreads();   // barrier2: xch[1] + hst[0] published

        // EARLY h0 store (threads 0..255; R0 layout) -- overlaps mv3 epilogue
        if (tid < 256 && t < T_ALL) {
            const int plane = (tid >> 7) & 1;
            const int bl = (tid >> 2) & 31, hq = tid & 3;
            const unsigned long long val =
                *(const unsigned long long*)&hst[0][plane][bl][hq * 4];
            unsigned short* basep = plane ? hLo0 : hHi0;
            unsigned long long* dst = (unsigned long long*)
                (basep + ((size_t)(t & 1) * 256 + bt * 32 + bl) * 512 + hgp * 16 + hq * 4);
            __hip_atomic_store(dst, val, __ATOMIC_RELAXED, __HIP_MEMORY_SCOPE_AGENT);
        }

        // mv3 epilogue: layer-1 update h1[t-1]
        if (mv == 3 && t >= 1) {
            #pragma unroll
            for (int rq = 0; rq < 4; ++rq) {
                const int hl = 2 * rq + half;
                float a[4];
                #pragma unroll
                for (int j = 0; j < 4; ++j)
                    a[j] = A0[rq * 4 + j]
                         + xch[1][hgi][j + 8 * rq + 4 * half][ml]
                         + ((const float*)&bs[rq])[j];
                const float ig = sigf(a[0]), fg = sigf(a[1]);
                const float gg = tanhf_hw(a[2]), og = sigf(a[3]);
                creg[rq] = fg * creg[rq] + ig * gg;
                const float h = og * tanhf_hw(creg[rq]);
                const unsigned short hh = f2bf(h);
                hst[1][0][ml][hgi * 8 + hl] = hh;
                hst[1][1][ml][hgi * 8 + hl] = f2bf(h - bf2f(hh));
            }
        }
        __syncthreads();   // barrier3: hst[1] published

        // h1 cooperative store (threads 256..511; R0 layout)
        if (tid >= 256 && t >= 1) {
            const int plane = (tid >> 7) & 1;
            const int bl = (tid >> 2) & 31, hq = tid & 3;
            const unsigned long long val =
                *(const unsigned long long*)&hst[1][plane][bl][hq * 4];
            unsigned short* basep = plane ? hLo1 : hHi1;
            unsigned long long* dst = (unsigned long long*)
                (basep + ((size_t)((t + 1) & 1) * 256 + bt * 32 + bl) * 512 + hgp * 16 + hq * 4);
            __hip_atomic_store(dst, val, __ATOMIC_RELAXED, __HIP_MEMORY_SCOPE_AGENT);
        }

        if (t < T_ALL) {
            __threadfence_block();       // drain h stores (vmcnt)
            __syncthreads();
            if (tid == 0)
                __hip_atomic_store(arr + (size_t)f * 16, t + 1,
                                   __ATOMIC_RELAXED, __HIP_MEMORY_SCOPE_AGENT);
            // wave 0 polls the 32 arrive slots -- skipped if pre-poll hit
            if (wv == 0 && !preOK) {
                int v = 0x7FFFFFFF;
                do {
                    if (lane < 32)
                        v = __hip_atomic_load(arr + ((size_t)bt * 32 + lane) * 16,
                                              __ATOMIC_RELAXED, __HIP_MEMORY_SCOPE_AGENT);
                    if (__all(lane >= 32 || v >= t + 1)) break;
                    __builtin_amdgcn_s_sleep(1);
                } while (true);
            }
            __syncthreads();
        }
    }
}

// heads: base_feat = h1[:,199] (slot 1, hi+lo reconstruct) -> cls/bbox + 2 zeros
__global__ __launch_bounds__(64) void heads(
    const unsigned short* __restrict__ hHi1, const unsigned short* __restrict__ hLo1,
    const float4* __restrict__ clsW, const float* __restrict__ clsb,
    const float4* __restrict__ bbW, const float* __restrict__ bbb,
    float* __restrict__ out)
{
    const int b = blockIdx.x, j = threadIdx.x;
    const size_t off = (size_t)(256 + b) * 512;   // slot 1
    if (j < 42) {
        const float4* w = (j < 40) ? (clsW + (size_t)j * 128) : (bbW + (size_t)(j - 40) * 128);
        float acc = 0.f;
        #pragma unroll 4
        for (int k4 = 0; k4 < 128; ++k4) {
            const ushort4 hh = *(const ushort4*)(hHi1 + off + k4 * 4);
            const ushort4 hl = *(const ushort4*)(hLo1 + off + k4 * 4);
            const float4 wv = w[k4];
            acc += (bf2f(hh.x) + bf2f(hl.x)) * wv.x
                 + (bf2f(hh.y) + bf2f(hl.y)) * wv.y
                 + (bf2f(hh.z) + bf2f(hl.z)) * wv.z
                 + (bf2f(hh.w) + bf2f(hl.w)) * wv.w;
        }
        if (j < 40) out[(size_t)b * 40 + j] = acc + clsb[j];
        else        out[10240 + (size_t)b * 2 + (j - 40)] = acc + bbb[j - 40];
    }
    if (b == 0 && (j == 62 || j == 63)) out[10752 + (j - 62)] = 0.f;
}

extern "C" void kernel_launch(void* const* d_in, const int* in_sizes, int n_in,
                              void* d_out, int out_size, void* d_ws, size_t ws_size,
                              hipStream_t stream) {
    const float* proposals = (const float*)d_in[2];
    const float* Wih0 = (const float*)d_in[4];
    const float* Whh0 = (const float*)d_in[5];
    const float* bih0 = (const float*)d_in[6];
    const float* bhh0 = (const float*)d_in[7];
    const float* Wih1 = (const float*)d_in[8];
    const float* Whh1 = (const float*)d_in[9];
    const float* bih1 = (const float*)d_in[10];
    const float* bhh1 = (const float*)d_in[11];
    const float* clsW = (const float*)d_in[12];
    const float* clsb = (const float*)d_in[13];
    const float* bbW  = (const float*)d_in[14];
    const float* bbb  = (const float*)d_in[15];

    char* ws = (char*)d_ws;
    unsigned short* Ahi  = (unsigned short*)(ws + A_HI_OFF);
    unsigned short* Alo  = (unsigned short*)(ws + A_LO_OFF);
    unsigned short* xHi  = (unsigned short*)(ws + X_HI_OFF);
    unsigned short* xLo  = (unsigned short*)(ws + X_LO_OFF);
    unsigned short* hHi0 = (unsigned short*)(ws + HHI0_OFF);
    unsigned short* hLo0 = (unsigned short*)(ws + HLO0_OFF);
    unsigned short* hHi1 = (unsigned short*)(ws + HHI1_OFF);
    unsigned short* hLo1 = (unsigned short*)(ws + HLO1_OFF);
    float4* b0pk = (float4*)(ws + B0PK_OFF);
    float4* b1pk = (float4*)(ws + B1PK_OFF);
    int*    arr  = (int*)(ws + ARR_OFF);

    hipMemsetAsync(arr, 0, ARR_BYTES, stream);

    pack_w<<<(int)A_FRAGS, 64, 0, stream>>>(Wih0, Whh0, Wih1, Whh1, Ahi, Alo);
    prep_x<<<200, 256, 0, stream>>>(proposals, xHi, xLo);
    pack_bias<<<1, 512, 0, stream>>>(bih0, bhh0, bih1, bhh1, b0pk, b1pk);

    lstm_scan<<<256, 512, 0, stream>>>(Ahi, Alo, xHi, xLo,
                                       hHi0, hLo0, hHi1, hLo1,
                                       b0pk, b1pk, arr);

    heads<<<256, 64, 0, stream>>>(hHi1, hLo1, (const float4*)clsW, clsb,
                                  (const float4*)bbW, bbb, (float*)d_out);
}

// Round 11
// 1890.106 us; speedup vs baseline: 1.2571x; 1.2571x over previous
//
#include <hip/hip_runtime.h>
#include <math.h>

#define T_ALL 200
#define ROWB  1040                 // 1024 B h-row + 16 B pad (16B-aligned)
#define QUAD  (32 * ROWB)          // 33,280 B per h quadrant

typedef __attribute__((ext_vector_type(8)))  _Float16 v8h;
typedef __attribute__((ext_vector_type(16))) float v16f;

typedef __attribute__((address_space(1))) const unsigned int g_u32;
typedef __attribute__((address_space(3))) unsigned int l_u32;

// device-coherent global->LDS: aux=16 (sc1) reads the L3 coherence point,
// bypassing the possibly-stale local L2 (proven in prior sessions).
__device__ __forceinline__ void gl2lds16_coh(const void* g, void* l) {
    __builtin_amdgcn_global_load_lds((g_u32*)g, (l_u32*)l, 16, 0, 16);
}

// fp16 helpers (hardware v_cvt, round-to-nearest-even)
__device__ __forceinline__ unsigned short f2h(float f) {
    _Float16 h = (_Float16)f;
    return *(unsigned short*)&h;
}
__device__ __forceinline__ float h2f(unsigned short s) {
    _Float16 h = *(_Float16*)&s;
    return (float)h;
}
// hardware-exp transcendentals (v_exp_f32): ~1e-7 error, saturation-safe
__device__ __forceinline__ float sigf(float x)  { return 1.0f / (1.0f + __expf(-x)); }
__device__ __forceinline__ float tanhf_hw(float x) {
    return 1.0f - 2.0f / (__expf(2.0f * x) + 1.0f);   // e=inf -> 1; e=0 -> -1
}

// ---- ws layout (bytes; unchanged from R9 -- Alo region now unused) ----
#define A_FRAGS   6656ULL
#define A_HI_OFF  0ULL
#define A_LO_OFF  (A_FRAGS * 1024ULL)
#define X_HI_OFF  (2ULL * A_FRAGS * 1024ULL)
#define X_BYTES   (200ULL * 256 * 128 * 2)
#define X_LO_OFF  (X_HI_OFF + X_BYTES)
#define H_BYTES   (2ULL * 256 * 512 * 2)
#define HHI0_OFF  (X_LO_OFF + X_BYTES)
#define HLO0_OFF  (HHI0_OFF + H_BYTES)
#define HHI1_OFF  (HLO0_OFF + H_BYTES)
#define HLO1_OFF  (HHI1_OFF + H_BYTES)
#define B0PK_OFF  (HLO1_OFF + H_BYTES)
#define B1PK_OFF  (B0PK_OFF + 8192ULL)
#define ARR_OFF   (B1PK_OFF + 8192ULL)
#define ARR_BYTES (256ULL * 64)              // one 64B-spread arrive slot per block

// Pack W rows into MFMA 32x32x16 A-fragment order, SINGLE fp16 plane.
// fp16's 11-bit mantissa (2^-11 rel) replaces the bf16 hi+lo pair -- halves
// the per-step L2 weight stream (the measured per-XCD L2 ceiling bound).
__global__ __launch_bounds__(64) void pack_w(
    const float* __restrict__ Wih0, const float* __restrict__ Whh0,
    const float* __restrict__ Wih1, const float* __restrict__ Whh1,
    unsigned short* __restrict__ Ahi)
{
    const int fi = blockIdx.x, lane = threadIdx.x;
    const float* W; int K, hg, c;
    if (fi < 512)       { W = Wih0; K = 128; hg = fi >> 3;          c = fi & 7;          }
    else if (fi < 2560) { W = Whh0; K = 512; hg = (fi - 512) >> 5;  c = (fi - 512) & 31; }
    else if (fi < 4608) { W = Wih1; K = 512; hg = (fi - 2560) >> 5; c = (fi - 2560) & 31;}
    else                { W = Whh1; K = 512; hg = (fi - 4608) >> 5; c = (fi - 4608) & 31;}
    const int m = lane & 31, half = lane >> 5;
    const int q = m & 3, hl = m >> 2;
    const int r = q * 512 + hg * 8 + hl;
    const int k0 = c * 16 + half * 8;
    const float* src = W + (size_t)r * K + k0;
    unsigned short* dh = Ahi + (size_t)fi * 512 + lane * 8;
    #pragma unroll
    for (int j = 0; j < 8; ++j)
        dh[j] = f2h(src[j]);
}

// proposals [b][t][c] fp32 -> xHi/xLo [t][b][c] fp16 hi + fp16 residual
// (two-plane fp16 ~ 2^-21 effective precision on x)
__global__ __launch_bounds__(256) void prep_x(const float* __restrict__ prop,
                                              unsigned short* __restrict__ xHi,
                                              unsigned short* __restrict__ xLo)
{
    const int t = blockIdx.x, b = threadIdx.x;
    const float* src = prop + ((size_t)b * 200 + t) * 128;
    unsigned short* dh = xHi + ((size_t)t * 256 + b) * 128;
    unsigned short* dl = xLo + ((size_t)t * 256 + b) * 128;
    #pragma unroll 4
    for (int c = 0; c < 128; ++c) {
        const float f = src[c];
        const unsigned short h = f2h(f);
        dh[c] = h;
        dl[c] = f2h(f - h2f(h));
    }
}

// bias packs: bpk[hid] = float4 over gates (i,f,g,o)
__global__ __launch_bounds__(512) void pack_bias(
    const float* __restrict__ bih0, const float* __restrict__ bhh0,
    const float* __restrict__ bih1, const float* __restrict__ bhh1,
    float4* __restrict__ b0, float4* __restrict__ b1)
{
    const int hid = threadIdx.x;
    float4 u, v;
    u.x = bih0[hid] + bhh0[hid];
    u.y = bih0[512 + hid] + bhh0[512 + hid];
    u.z = bih0[1024 + hid] + bhh0[1024 + hid];
    u.w = bih0[1536 + hid] + bhh0[1536 + hid];
    v.x = bih1[hid] + bhh1[hid];
    v.y = bih1[512 + hid] + bhh1[512 + hid];
    v.z = bih1[1024 + hid] + bhh1[1024 + hid];
    v.w = bih1[1536 + hid] + bhh1[1536 + hid];
    b0[hid] = u; b1[hid] = v;
}

// PERSISTENT fused scan -- R9 structure (verified 2297us: single accumulator,
// 2-row weight prefetch, R5 tail protocol), with the matvec numerics switched
// from 3-product split-bf16 to FP16 SINGLE-PLANE WEIGHTS:
//   w*h ~= w16*hh + w16*hl   (weights fp16 1 plane; h,x fp16 hi+lo planes)
// Halves the per-step L2 weight stream (region A's measured per-XCD-L2-
// ceiling bound: 13.3 -> 6.7 MB/XCD/step) and cuts MFMA count 96 -> 64 per
// recurrent wave.  Staging, stores, LDS layout, and the sync protocol are
// byte-identical to R9.  Expected absmax rise: 7.6e-6 -> ~1e-4 (fp16 weight
// rounding 2^-11); revert to R9 if the harness threshold rejects it.
__global__ __launch_bounds__(512) void lstm_scan(
    const unsigned short* __restrict__ Ahi,
    const unsigned short* __restrict__ xHi, const unsigned short* __restrict__ xLo,
    unsigned short* __restrict__ hHi0, unsigned short* __restrict__ hLo0,
    unsigned short* __restrict__ hHi1, unsigned short* __restrict__ hLo1,
    const float4* __restrict__ b0pk, const float4* __restrict__ b1pk,
    int* __restrict__ arr)
{
    __shared__ __align__(16) unsigned char dbuf[4 * QUAD];       // 133,120 B
    __shared__ float xch[2][2][32][32];                          //  16,384 B
    __shared__ __align__(16) unsigned short hst[2][2][32][16];   //   4,096 B

    const int tid  = threadIdx.x;
    const int wv   = tid >> 6, lane = tid & 63;
    const int mv   = wv >> 1, hgi = wv & 1;
    const int f    = blockIdx.x;                   // 0..255
    const int hgp  = (f & 7) * 4 + ((f >> 3) & 3); // 4 hg-pairs per XCD
    const int bt   = f >> 5;                       // batch tile 0..7 = sync group
    const int hg   = hgp * 2 + hgi;                // hid group 0..63
    const int ml   = lane & 31, half = lane >> 5;
    const int gslot = f & 31;                      // our slot within the group

    int fbase;
    if (mv == 0)      fbase = hg * 8;
    else if (mv == 1) fbase = 512 + hg * 32;
    else if (mv == 2) fbase = 2560 + hg * 32;
    else              fbase = 4608 + hg * 32;

    float4 bs[4];
    #pragma unroll
    for (int rq = 0; rq < 4; ++rq) {
        const int hid = hg * 8 + 2 * rq + half;
        bs[rq] = (mv == 1) ? b0pk[hid] : (mv == 3) ? b1pk[hid]
                                       : make_float4(0.f, 0.f, 0.f, 0.f);
    }
    float creg[4] = {0.f, 0.f, 0.f, 0.f};

    for (int t = 0; t <= T_ALL; ++t) {
        const int rs0 = (t + 1) & 1;   // h0[t-1] slot
        const int rs1 = t & 1;         // h1[t-2] slot
        const unsigned short* srcq[4] = {
            hHi0 + ((size_t)rs0 * 256 + bt * 32) * 512,
            hLo0 + ((size_t)rs0 * 256 + bt * 32) * 512,
            hHi1 + ((size_t)rs1 * 256 + bt * 32) * 512,
            hLo1 + ((size_t)rs1 * 256 + bt * 32) * 512 };

        // ---- single staging burst: 128 rows (4 quadrants x 32 batches) ----
        #pragma unroll
        for (int j = 0; j < 16; ++j) {
            const int row = wv * 16 + j;
            const int q = row >> 5, r = row & 31;
            gl2lds16_coh(srcq[q] + (size_t)r * 512 + lane * 8,
                         &dbuf[q * QUAD + r * ROWB]);
        }

        // recurrent waves: prefetch weight rows c=0,1 (drain with staging)
        v8h pf0h, pf1h;
        if (mv >= 1) {
            pf0h = *(const v8h*)(Ahi + ((size_t)(fbase + 0)) * 512 + lane * 8);
            pf1h = *(const v8h*)(Ahi + ((size_t)(fbase + 1)) * 512 + lane * 8);
        }

        v16f A0;
        #pragma unroll
        for (int i = 0; i < 16; ++i) A0[i] = 0.f;

        // mv0: x-matvec (plain loads, independent of dbuf) before the drain
        if (mv == 0 && t < T_ALL) {
            const unsigned short* xh = xHi + ((size_t)t * 256 + bt * 32 + ml) * 128 + half * 8;
            const unsigned short* xl = xLo + ((size_t)t * 256 + bt * 32 + ml) * 128 + half * 8;
            #pragma unroll
            for (int c = 0; c < 8; ++c) {
                const v8h ah = *(const v8h*)(Ahi + ((size_t)(fbase + c)) * 512 + lane * 8);
                const v8h bh = *(const v8h*)(xh + c * 16);
                const v8h bl = *(const v8h*)(xl + c * 16);
                A0 = __builtin_amdgcn_mfma_f32_32x32x16_f16(ah, bh, A0, 0, 0, 0);
                A0 = __builtin_amdgcn_mfma_f32_32x32x16_f16(ah, bl, A0, 0, 0, 0);
            }
            #pragma unroll
            for (int r = 0; r < 16; ++r)
                xch[0][hgi][(r & 3) + 8 * (r >> 2) + 4 * half][ml] = A0[r];
            #pragma unroll
            for (int i = 0; i < 16; ++i) A0[i] = 0.f;
        }
        __syncthreads();   // barrier1: staging + prefetch drained, xch[0] published

        // wave 0 idle window: bounded pre-poll (byte-identical to R5/R9)
        bool preOK = false;
        if (wv == 0 && t < T_ALL) {
            #pragma unroll 1
            for (int it = 0; it < 4 && !preOK; ++it) {
                int v = 0x7FFFFFFF;
                if (lane < 32)
                    v = __hip_atomic_load(arr + ((size_t)bt * 32 + lane) * 16,
                                          __ATOMIC_RELAXED, __HIP_MEMORY_SCOPE_AGENT);
                preOK = __all(lane >= 32 || lane == gslot || v >= t + 1);
                if (!preOK) __builtin_amdgcn_s_sleep(1);
            }
        }

        // ---- recurrent matvecs from LDS (h0 for mv1/mv2, h1 for mv3) ----
        const bool a12 = (mv == 1) ? (t >= 1 && t < T_ALL)
                       : (mv == 2) ? (t >= 1) : false;
        const bool a3  = (mv == 3) && (t >= 2);
        if (a12 || a3) {
            const unsigned char* qhi = dbuf + (mv == 3 ? 2 : 0) * QUAD;
            const unsigned char* qlo = qhi + QUAD;
            // c = 0,1 peeled: weights already in registers (prefetched)
            {
                const v8h bh0 = *(const v8h*)(qhi + ml * ROWB + 0 * 32 + half * 16);
                const v8h bl0 = *(const v8h*)(qlo + ml * ROWB + 0 * 32 + half * 16);
                A0 = __builtin_amdgcn_mfma_f32_32x32x16_f16(pf0h, bh0, A0, 0, 0, 0);
                A0 = __builtin_amdgcn_mfma_f32_32x32x16_f16(pf0h, bl0, A0, 0, 0, 0);
                const v8h bh1 = *(const v8h*)(qhi + ml * ROWB + 1 * 32 + half * 16);
                const v8h bl1 = *(const v8h*)(qlo + ml * ROWB + 1 * 32 + half * 16);
                A0 = __builtin_amdgcn_mfma_f32_32x32x16_f16(pf1h, bh1, A0, 0, 0, 0);
                A0 = __builtin_amdgcn_mfma_f32_32x32x16_f16(pf1h, bl1, A0, 0, 0, 0);
            }
            #pragma unroll 6
            for (int c = 2; c < 32; ++c) {
                const v8h ah = *(const v8h*)(Ahi + ((size_t)(fbase + c)) * 512 + lane * 8);
                const v8h bh = *(const v8h*)(qhi + ml * ROWB + c * 32 + half * 16);
                const v8h bl = *(const v8h*)(qlo + ml * ROWB + c * 32 + half * 16);
                A0 = __builtin_amdgcn_mfma_f32_32x32x16_f16(ah, bh, A0, 0, 0, 0);
                A0 = __builtin_amdgcn_mfma_f32_32x32x16_f16(ah, bl, A0, 0, 0, 0);
            }
        }

        // mv1: full epilogue now (xch[0] already published)
        if (mv == 1 && t < T_ALL) {
            #pragma unroll
            for (int rq = 0; rq < 4; ++rq) {
                const int hl = 2 * rq + half;
                float a[4];
                #pragma unroll
                for (int j = 0; j < 4; ++j)
                    a[j] = A0[rq * 4 + j]
                         + xch[0][hgi][j + 8 * rq + 4 * half][ml]
                         + ((const float*)&bs[rq])[j];
                const float ig = sigf(a[0]), fg = sigf(a[1]);
                const float gg = tanhf_hw(a[2]), og = sigf(a[3]);
                creg[rq] = fg * creg[rq] + ig * gg;
                const float h = og * tanhf_hw(creg[rq]);
                const unsigned short hh = f2h(h);
                hst[0][0][ml][hgi * 8 + hl] = hh;
                hst[0][1][ml][hgi * 8 + hl] = f2h(h - h2f(hh));
            }
        }
        if (mv == 2 && t >= 1) {
            #pragma unroll
            for (int r = 0; r < 16; ++r)
                xch[1][hgi][(r & 3) + 8 * (r >> 2) + 4 * half][ml] = A0[r];
        }
        __syncthreads();   // barrier2: xch[1] + hst[0] published

        // EARLY h0 store (threads 0..255; R0 layout) -- overlaps mv3 epilogue
        if (tid < 256 && t < T_ALL) {
            const int plane = (tid >> 7) & 1;
            const int bl = (tid >> 2) & 31, hq = tid & 3;
            const unsigned long long val =
                *(const unsigned long long*)&hst[0][plane][bl][hq * 4];
            unsigned short* basep = plane ? hLo0 : hHi0;
            unsigned long long* dst = (unsigned long long*)
                (basep + ((size_t)(t & 1) * 256 + bt * 32 + bl) * 512 + hgp * 16 + hq * 4);
            __hip_atomic_store(dst, val, __ATOMIC_RELAXED, __HIP_MEMORY_SCOPE_AGENT);
        }

        // mv3 epilogue: layer-1 update h1[t-1]
        if (mv == 3 && t >= 1) {
            #pragma unroll
            for (int rq = 0; rq < 4; ++rq) {
                const int hl = 2 * rq + half;
                float a[4];
                #pragma unroll
                for (int j = 0; j < 4; ++j)
                    a[j] = A0[rq * 4 + j]
                         + xch[1][hgi][j + 8 * rq + 4 * half][ml]
                         + ((const float*)&bs[rq])[j];
                const float ig = sigf(a[0]), fg = sigf(a[1]);
                const float gg = tanhf_hw(a[2]), og = sigf(a[3]);
                creg[rq] = fg * creg[rq] + ig * gg;
                const float h = og * tanhf_hw(creg[rq]);
                const unsigned short hh = f2h(h);
                hst[1][0][ml][hgi * 8 + hl] = hh;
                hst[1][1][ml][hgi * 8 + hl] = f2h(h - h2f(hh));
            }
        }
        __syncthreads();   // barrier3: hst[1] published

        // h1 cooperative store (threads 256..511; R0 layout)
        if (tid >= 256 && t >= 1) {
            const int plane = (tid >> 7) & 1;
            const int bl = (tid >> 2) & 31, hq = tid & 3;
            const unsigned long long val =
                *(const unsigned long long*)&hst[1][plane][bl][hq * 4];
            unsigned short* basep = plane ? hLo1 : hHi1;
            unsigned long long* dst = (unsigned long long*)
                (basep + ((size_t)((t + 1) & 1) * 256 + bt * 32 + bl) * 512 + hgp * 16 + hq * 4);
            __hip_atomic_store(dst, val, __ATOMIC_RELAXED, __HIP_MEMORY_SCOPE_AGENT);
        }

        if (t < T_ALL) {
            __threadfence_block();       // drain h stores (vmcnt)
            __syncthreads();
            if (tid == 0)
                __hip_atomic_store(arr + (size_t)f * 16, t + 1,
                                   __ATOMIC_RELAXED, __HIP_MEMORY_SCOPE_AGENT);
            // wave 0 polls the 32 arrive slots -- skipped if pre-poll hit
            if (wv == 0 && !preOK) {
                int v = 0x7FFFFFFF;
                do {
                    if (lane < 32)
                        v = __hip_atomic_load(arr + ((size_t)bt * 32 + lane) * 16,
                                              __ATOMIC_RELAXED, __HIP_MEMORY_SCOPE_AGENT);
                    if (__all(lane >= 32 || v >= t + 1)) break;
                    __builtin_amdgcn_s_sleep(1);
                } while (true);
            }
            __syncthreads();
        }
    }
}

// heads: base_feat = h1[:,199] (slot 1, fp16 hi+lo reconstruct) -> cls/bbox
__global__ __launch_bounds__(64) void heads(
    const unsigned short* __restrict__ hHi1, const unsigned short* __restrict__ hLo1,
    const float4* __restrict__ clsW, const float* __restrict__ clsb,
    const float4* __restrict__ bbW, const float* __restrict__ bbb,
    float* __restrict__ out)
{
    const int b = blockIdx.x, j = threadIdx.x;
    const size_t off = (size_t)(256 + b) * 512;   // slot 1
    if (j < 42) {
        const float4* w = (j < 40) ? (clsW + (size_t)j * 128) : (bbW + (size_t)(j - 40) * 128);
        float acc = 0.f;
        #pragma unroll 4
        for (int k4 = 0; k4 < 128; ++k4) {
            const ushort4 hh = *(const ushort4*)(hHi1 + off + k4 * 4);
            const ushort4 hl = *(const ushort4*)(hLo1 + off + k4 * 4);
            const float4 wv = w[k4];
            acc += (h2f(hh.x) + h2f(hl.x)) * wv.x
                 + (h2f(hh.y) + h2f(hl.y)) * wv.y
                 + (h2f(hh.z) + h2f(hl.z)) * wv.z
                 + (h2f(hh.w) + h2f(hl.w)) * wv.w;
        }
        if (j < 40) out[(size_t)b * 40 + j] = acc + clsb[j];
        else        out[10240 + (size_t)b * 2 + (j - 40)] = acc + bbb[j - 40];
    }
    if (b == 0 && (j == 62 || j == 63)) out[10752 + (j - 62)] = 0.f;
}

extern "C" void kernel_launch(void* const* d_in, const int* in_sizes, int n_in,
                              void* d_out, int out_size, void* d_ws, size_t ws_size,
                              hipStream_t stream) {
    const float* proposals = (const float*)d_in[2];
    const float* Wih0 = (const float*)d_in[4];
    const float* Whh0 = (const float*)d_in[5];
    const float* bih0 = (const float*)d_in[6];
    const float* bhh0 = (const float*)d_in[7];
    const float* Wih1 = (const float*)d_in[8];
    const float* Whh1 = (const float*)d_in[9];
    const float* bih1 = (const float*)d_in[10];
    const float* bhh1 = (const float*)d_in[11];
    const float* clsW = (const float*)d_in[12];
    const float* clsb = (const float*)d_in[13];
    const float* bbW  = (const float*)d_in[14];
    const float* bbb  = (const float*)d_in[15];

    char* ws = (char*)d_ws;
    unsigned short* Ahi  = (unsigned short*)(ws + A_HI_OFF);
    unsigned short* xHi  = (unsigned short*)(ws + X_HI_OFF);
    unsigned short* xLo  = (unsigned short*)(ws + X_LO_OFF);
    unsigned short* hHi0 = (unsigned short*)(ws + HHI0_OFF);
    unsigned short* hLo0 = (unsigned short*)(ws + HLO0_OFF);
    unsigned short* hHi1 = (unsigned short*)(ws + HHI1_OFF);
    unsigned short* hLo1 = (unsigned short*)(ws + HLO1_OFF);
    float4* b0pk = (float4*)(ws + B0PK_OFF);
    float4* b1pk = (float4*)(ws + B1PK_OFF);
    int*    arr  = (int*)(ws + ARR_OFF);

    hipMemsetAsync(arr, 0, ARR_BYTES, stream);

    pack_w<<<(int)A_FRAGS, 64, 0, stream>>>(Wih0, Whh0, Wih1, Whh1, Ahi);
    prep_x<<<200, 256, 0, stream>>>(proposals, xHi, xLo);
    pack_bias<<<1, 512, 0, stream>>>(bih0, bhh0, bih1, bhh1, b0pk, b1pk);

    lstm_scan<<<256, 512, 0, stream>>>(Ahi, xHi, xLo,
                                       hHi0, hLo0, hHi1, hLo1,
                                       b0pk, b1pk, arr);

    heads<<<256, 64, 0, stream>>>(hHi1, hLo1, (const float4*)clsW, clsb,
                                  (const float4*)bbW, bbb, (float*)d_out);
}

// Round 12
// 1624.216 us; speedup vs baseline: 1.4628x; 1.1637x over previous
//
#include <hip/hip_runtime.h>
#include <math.h>

#define T_ALL 200
#define ROWB  1040                 // 1024 B h-row + 16 B pad (16B-aligned)
#define QUAD  (32 * ROWB)          // 33,280 B per h quadrant

typedef __attribute__((ext_vector_type(8)))  _Float16 v8h;
typedef __attribute__((ext_vector_type(16))) float v16f;

typedef __attribute__((address_space(1))) const unsigned int g_u32;
typedef __attribute__((address_space(3))) unsigned int l_u32;

// device-coherent global->LDS: aux=16 (sc1) reads the L3 coherence point,
// bypassing the possibly-stale local L2 (proven in prior sessions).
__device__ __forceinline__ void gl2lds16_coh(const void* g, void* l) {
    __builtin_amdgcn_global_load_lds((g_u32*)g, (l_u32*)l, 16, 0, 16);
}

// fp16 helpers (hardware v_cvt, round-to-nearest-even)
__device__ __forceinline__ unsigned short f2h(float f) {
    _Float16 h = (_Float16)f;
    return *(unsigned short*)&h;
}
__device__ __forceinline__ float h2f(unsigned short s) {
    _Float16 h = *(_Float16*)&s;
    return (float)h;
}
// hardware-exp transcendentals (v_exp_f32): ~1e-7 error, saturation-safe
__device__ __forceinline__ float sigf(float x)  { return 1.0f / (1.0f + __expf(-x)); }
__device__ __forceinline__ float tanhf_hw(float x) {
    return 1.0f - 2.0f / (__expf(2.0f * x) + 1.0f);   // e=inf -> 1; e=0 -> -1
}

// ---- ws layout (bytes; unchanged -- Alo/hLo0 regions now unused) ----
#define A_FRAGS   6656ULL
#define A_HI_OFF  0ULL
#define A_LO_OFF  (A_FRAGS * 1024ULL)
#define X_HI_OFF  (2ULL * A_FRAGS * 1024ULL)
#define X_BYTES   (200ULL * 256 * 128 * 2)
#define X_LO_OFF  (X_HI_OFF + X_BYTES)
#define H_BYTES   (2ULL * 256 * 512 * 2)
#define HHI0_OFF  (X_LO_OFF + X_BYTES)
#define HLO0_OFF  (HHI0_OFF + H_BYTES)
#define HHI1_OFF  (HLO0_OFF + H_BYTES)
#define HLO1_OFF  (HHI1_OFF + H_BYTES)
#define B0PK_OFF  (HLO1_OFF + H_BYTES)
#define B1PK_OFF  (B0PK_OFF + 8192ULL)
#define ARR_OFF   (B1PK_OFF + 8192ULL)
#define ARR_BYTES (256ULL * 64)              // one 64B-spread arrive slot per block

// Pack W rows into MFMA 32x32x16 A-fragment order, SINGLE fp16 plane.
__global__ __launch_bounds__(64) void pack_w(
    const float* __restrict__ Wih0, const float* __restrict__ Whh0,
    const float* __restrict__ Wih1, const float* __restrict__ Whh1,
    unsigned short* __restrict__ Ahi)
{
    const int fi = blockIdx.x, lane = threadIdx.x;
    const float* W; int K, hg, c;
    if (fi < 512)       { W = Wih0; K = 128; hg = fi >> 3;          c = fi & 7;          }
    else if (fi < 2560) { W = Whh0; K = 512; hg = (fi - 512) >> 5;  c = (fi - 512) & 31; }
    else if (fi < 4608) { W = Wih1; K = 512; hg = (fi - 2560) >> 5; c = (fi - 2560) & 31;}
    else                { W = Whh1; K = 512; hg = (fi - 4608) >> 5; c = (fi - 4608) & 31;}
    const int m = lane & 31, half = lane >> 5;
    const int q = m & 3, hl = m >> 2;
    const int r = q * 512 + hg * 8 + hl;
    const int k0 = c * 16 + half * 8;
    const float* src = W + (size_t)r * K + k0;
    unsigned short* dh = Ahi + (size_t)fi * 512 + lane * 8;
    #pragma unroll
    for (int j = 0; j < 8; ++j)
        dh[j] = f2h(src[j]);
}

// proposals [b][t][c] fp32 -> xHi/xLo [t][b][c] fp16 hi + fp16 residual
__global__ __launch_bounds__(256) void prep_x(const float* __restrict__ prop,
                                              unsigned short* __restrict__ xHi,
                                              unsigned short* __restrict__ xLo)
{
    const int t = blockIdx.x, b = threadIdx.x;
    const float* src = prop + ((size_t)b * 200 + t) * 128;
    unsigned short* dh = xHi + ((size_t)t * 256 + b) * 128;
    unsigned short* dl = xLo + ((size_t)t * 256 + b) * 128;
    #pragma unroll 4
    for (int c = 0; c < 128; ++c) {
        const float f = src[c];
        const unsigned short h = f2h(f);
        dh[c] = h;
        dl[c] = f2h(f - h2f(h));
    }
}

// bias packs: bpk[hid] = float4 over gates (i,f,g,o)
__global__ __launch_bounds__(512) void pack_bias(
    const float* __restrict__ bih0, const float* __restrict__ bhh0,
    const float* __restrict__ bih1, const float* __restrict__ bhh1,
    float4* __restrict__ b0, float4* __restrict__ b1)
{
    const int hid = threadIdx.x;
    float4 u, v;
    u.x = bih0[hid] + bhh0[hid];
    u.y = bih0[512 + hid] + bhh0[512 + hid];
    u.z = bih0[1024 + hid] + bhh0[1024 + hid];
    u.w = bih0[1536 + hid] + bhh0[1536 + hid];
    v.x = bih1[hid] + bhh1[hid];
    v.y = bih1[512 + hid] + bhh1[512 + hid];
    v.z = bih1[1024 + hid] + bhh1[1024 + hid];
    v.w = bih1[1536 + hid] + bhh1[1536 + hid];
    b0[hid] = u; b1[hid] = v;
}

// PERSISTENT fused scan -- R11 structure (verified 1890us: fp16 single-plane
// weights, single accumulator, 2-row prefetch, R5 tail protocol).  This
// round: SINGLE-PLANE h on the recurrent path.  h (|h|~0.05) is carried as
// one fp16 plane through staging + matvec -- error ~5.5e-6/step into
// pre-activations, same magnitude as the fp16 weight rounding that measured
// ZERO absmax impact in R11.  h1's lo-plane is still STORED each step (heads
// reconstructs the final output hi+lo) but never staged back.
//  * staging: 128 -> 64 rows (32 -> 16 MB/step aggregate, the largest term)
//  * recurrent MFMA: 64 -> 32 per wave;  * dbuf: 4 -> 2 quadrants (LDS 87KB)
//  * h0 store: hi only (128 threads, same 32B-sector write-combining)
// Sync protocol, arrive/poll, store discipline byte-identical to R11.
__global__ __launch_bounds__(512) void lstm_scan(
    const unsigned short* __restrict__ Ahi,
    const unsigned short* __restrict__ xHi, const unsigned short* __restrict__ xLo,
    unsigned short* __restrict__ hHi0,
    unsigned short* __restrict__ hHi1, unsigned short* __restrict__ hLo1,
    const float4* __restrict__ b0pk, const float4* __restrict__ b1pk,
    int* __restrict__ arr)
{
    __shared__ __align__(16) unsigned char dbuf[2 * QUAD];       //  66,560 B
    __shared__ float xch[2][2][32][32];                          //  16,384 B
    __shared__ __align__(16) unsigned short hst[2][2][32][16];   //   4,096 B

    const int tid  = threadIdx.x;
    const int wv   = tid >> 6, lane = tid & 63;
    const int mv   = wv >> 1, hgi = wv & 1;
    const int f    = blockIdx.x;                   // 0..255
    const int hgp  = (f & 7) * 4 + ((f >> 3) & 3); // 4 hg-pairs per XCD
    const int bt   = f >> 5;                       // batch tile 0..7 = sync group
    const int hg   = hgp * 2 + hgi;                // hid group 0..63
    const int ml   = lane & 31, half = lane >> 5;
    const int gslot = f & 31;                      // our slot within the group

    int fbase;
    if (mv == 0)      fbase = hg * 8;
    else if (mv == 1) fbase = 512 + hg * 32;
    else if (mv == 2) fbase = 2560 + hg * 32;
    else              fbase = 4608 + hg * 32;

    float4 bs[4];
    #pragma unroll
    for (int rq = 0; rq < 4; ++rq) {
        const int hid = hg * 8 + 2 * rq + half;
        bs[rq] = (mv == 1) ? b0pk[hid] : (mv == 3) ? b1pk[hid]
                                       : make_float4(0.f, 0.f, 0.f, 0.f);
    }
    float creg[4] = {0.f, 0.f, 0.f, 0.f};

    for (int t = 0; t <= T_ALL; ++t) {
        const int rs0 = (t + 1) & 1;   // h0[t-1] slot
        const int rs1 = t & 1;         // h1[t-2] slot
        const unsigned short* srcq[2] = {
            hHi0 + ((size_t)rs0 * 256 + bt * 32) * 512,
            hHi1 + ((size_t)rs1 * 256 + bt * 32) * 512 };

        // ---- staging burst: 64 rows (2 hi quadrants x 32 batches) ----
        #pragma unroll
        for (int j = 0; j < 8; ++j) {
            const int row = wv * 8 + j;
            const int q = row >> 5, r = row & 31;
            gl2lds16_coh(srcq[q] + (size_t)r * 512 + lane * 8,
                         &dbuf[q * QUAD + r * ROWB]);
        }

        // recurrent waves: prefetch weight rows c=0,1 (drain with staging)
        v8h pf0h, pf1h;
        if (mv >= 1) {
            pf0h = *(const v8h*)(Ahi + ((size_t)(fbase + 0)) * 512 + lane * 8);
            pf1h = *(const v8h*)(Ahi + ((size_t)(fbase + 1)) * 512 + lane * 8);
        }

        v16f A0;
        #pragma unroll
        for (int i = 0; i < 16; ++i) A0[i] = 0.f;

        // mv0: x-matvec (plain loads, independent of dbuf) before the drain
        if (mv == 0 && t < T_ALL) {
            const unsigned short* xh = xHi + ((size_t)t * 256 + bt * 32 + ml) * 128 + half * 8;
            const unsigned short* xl = xLo + ((size_t)t * 256 + bt * 32 + ml) * 128 + half * 8;
            #pragma unroll
            for (int c = 0; c < 8; ++c) {
                const v8h ah = *(const v8h*)(Ahi + ((size_t)(fbase + c)) * 512 + lane * 8);
                const v8h bh = *(const v8h*)(xh + c * 16);
                const v8h bl = *(const v8h*)(xl + c * 16);
                A0 = __builtin_amdgcn_mfma_f32_32x32x16_f16(ah, bh, A0, 0, 0, 0);
                A0 = __builtin_amdgcn_mfma_f32_32x32x16_f16(ah, bl, A0, 0, 0, 0);
            }
            #pragma unroll
            for (int r = 0; r < 16; ++r)
                xch[0][hgi][(r & 3) + 8 * (r >> 2) + 4 * half][ml] = A0[r];
            #pragma unroll
            for (int i = 0; i < 16; ++i) A0[i] = 0.f;
        }
        __syncthreads();   // barrier1: staging + prefetch drained, xch[0] published

        // wave 0 idle window: bounded pre-poll (byte-identical to R5/R9/R11)
        bool preOK = false;
        if (wv == 0 && t < T_ALL) {
            #pragma unroll 1
            for (int it = 0; it < 4 && !preOK; ++it) {
                int v = 0x7FFFFFFF;
                if (lane < 32)
                    v = __hip_atomic_load(arr + ((size_t)bt * 32 + lane) * 16,
                                          __ATOMIC_RELAXED, __HIP_MEMORY_SCOPE_AGENT);
                preOK = __all(lane >= 32 || lane == gslot || v >= t + 1);
                if (!preOK) __builtin_amdgcn_s_sleep(1);
            }
        }

        // ---- recurrent matvecs from LDS (h0-hi for mv1/mv2, h1-hi for mv3) ----
        const bool a12 = (mv == 1) ? (t >= 1 && t < T_ALL)
                       : (mv == 2) ? (t >= 1) : false;
        const bool a3  = (mv == 3) && (t >= 2);
        if (a12 || a3) {
            const unsigned char* qhi = dbuf + (mv == 3 ? 1 : 0) * QUAD;
            // c = 0,1 peeled: weights already in registers (prefetched)
            {
                const v8h bh0 = *(const v8h*)(qhi + ml * ROWB + 0 * 32 + half * 16);
                A0 = __builtin_amdgcn_mfma_f32_32x32x16_f16(pf0h, bh0, A0, 0, 0, 0);
                const v8h bh1 = *(const v8h*)(qhi + ml * ROWB + 1 * 32 + half * 16);
                A0 = __builtin_amdgcn_mfma_f32_32x32x16_f16(pf1h, bh1, A0, 0, 0, 0);
            }
            #pragma unroll 6
            for (int c = 2; c < 32; ++c) {
                const v8h ah = *(const v8h*)(Ahi + ((size_t)(fbase + c)) * 512 + lane * 8);
                const v8h bh = *(const v8h*)(qhi + ml * ROWB + c * 32 + half * 16);
                A0 = __builtin_amdgcn_mfma_f32_32x32x16_f16(ah, bh, A0, 0, 0, 0);
            }
        }

        // mv1: full epilogue now (xch[0] already published); h0 hi-plane only
        if (mv == 1 && t < T_ALL) {
            #pragma unroll
            for (int rq = 0; rq < 4; ++rq) {
                const int hl = 2 * rq + half;
                float a[4];
                #pragma unroll
                for (int j = 0; j < 4; ++j)
                    a[j] = A0[rq * 4 + j]
                         + xch[0][hgi][j + 8 * rq + 4 * half][ml]
                         + ((const float*)&bs[rq])[j];
                const float ig = sigf(a[0]), fg = sigf(a[1]);
                const float gg = tanhf_hw(a[2]), og = sigf(a[3]);
                creg[rq] = fg * creg[rq] + ig * gg;
                const float h = og * tanhf_hw(creg[rq]);
                hst[0][0][ml][hgi * 8 + hl] = f2h(h);
            }
        }
        if (mv == 2 && t >= 1) {
            #pragma unroll
            for (int r = 0; r < 16; ++r)
                xch[1][hgi][(r & 3) + 8 * (r >> 2) + 4 * half][ml] = A0[r];
        }
        __syncthreads();   // barrier2: xch[1] + hst[0] published

        // EARLY h0 store (threads 0..127; hi plane only, R0 discipline)
        if (tid < 128 && t < T_ALL) {
            const int bl = (tid >> 2) & 31, hq = tid & 3;
            const unsigned long long val =
                *(const unsigned long long*)&hst[0][0][bl][hq * 4];
            unsigned long long* dst = (unsigned long long*)
                (hHi0 + ((size_t)(t & 1) * 256 + bt * 32 + bl) * 512 + hgp * 16 + hq * 4);
            __hip_atomic_store(dst, val, __ATOMIC_RELAXED, __HIP_MEMORY_SCOPE_AGENT);
        }

        // mv3 epilogue: layer-1 update h1[t-1] (hi + lo; lo feeds heads only)
        if (mv == 3 && t >= 1) {
            #pragma unroll
            for (int rq = 0; rq < 4; ++rq) {
                const int hl = 2 * rq + half;
                float a[4];
                #pragma unroll
                for (int j = 0; j < 4; ++j)
                    a[j] = A0[rq * 4 + j]
                         + xch[1][hgi][j + 8 * rq + 4 * half][ml]
                         + ((const float*)&bs[rq])[j];
                const float ig = sigf(a[0]), fg = sigf(a[1]);
                const float gg = tanhf_hw(a[2]), og = sigf(a[3]);
                creg[rq] = fg * creg[rq] + ig * gg;
                const float h = og * tanhf_hw(creg[rq]);
                const unsigned short hh = f2h(h);
                hst[1][0][ml][hgi * 8 + hl] = hh;
                hst[1][1][ml][hgi * 8 + hl] = f2h(h - h2f(hh));
            }
        }
        __syncthreads();   // barrier3: hst[1] published

        // h1 cooperative store (threads 256..511; hi+lo, R0 layout)
        if (tid >= 256 && t >= 1) {
            const int plane = (tid >> 7) & 1;
            const int bl = (tid >> 2) & 31, hq = tid & 3;
            const unsigned long long val =
                *(const unsigned long long*)&hst[1][plane][bl][hq * 4];
            unsigned short* basep = plane ? hLo1 : hHi1;
            unsigned long long* dst = (unsigned long long*)
                (basep + ((size_t)((t + 1) & 1) * 256 + bt * 32 + bl) * 512 + hgp * 16 + hq * 4);
            __hip_atomic_store(dst, val, __ATOMIC_RELAXED, __HIP_MEMORY_SCOPE_AGENT);
        }

        if (t < T_ALL) {
            __threadfence_block();       // drain h stores (vmcnt)
            __syncthreads();
            if (tid == 0)
                __hip_atomic_store(arr + (size_t)f * 16, t + 1,
                                   __ATOMIC_RELAXED, __HIP_MEMORY_SCOPE_AGENT);
            // wave 0 polls the 32 arrive slots -- skipped if pre-poll hit
            if (wv == 0 && !preOK) {
                int v = 0x7FFFFFFF;
                do {
                    if (lane < 32)
                        v = __hip_atomic_load(arr + ((size_t)bt * 32 + lane) * 16,
                                              __ATOMIC_RELAXED, __HIP_MEMORY_SCOPE_AGENT);
                    if (__all(lane >= 32 || v >= t + 1)) break;
                    __builtin_amdgcn_s_sleep(1);
                } while (true);
            }
            __syncthreads();
        }
    }
}

// heads: base_feat = h1[:,199] (slot 1, fp16 hi+lo reconstruct) -> cls/bbox
__global__ __launch_bounds__(64) void heads(
    const unsigned short* __restrict__ hHi1, const unsigned short* __restrict__ hLo1,
    const float4* __restrict__ clsW, const float* __restrict__ clsb,
    const float4* __restrict__ bbW, const float* __restrict__ bbb,
    float* __restrict__ out)
{
    const int b = blockIdx.x, j = threadIdx.x;
    const size_t off = (size_t)(256 + b) * 512;   // slot 1
    if (j < 42) {
        const float4* w = (j < 40) ? (clsW + (size_t)j * 128) : (bbW + (size_t)(j - 40) * 128);
        float acc = 0.f;
        #pragma unroll 4
        for (int k4 = 0; k4 < 128; ++k4) {
            const ushort4 hh = *(const ushort4*)(hHi1 + off + k4 * 4);
            const ushort4 hl = *(const ushort4*)(hLo1 + off + k4 * 4);
            const float4 wv = w[k4];
            acc += (h2f(hh.x) + h2f(hl.x)) * wv.x
                 + (h2f(hh.y) + h2f(hl.y)) * wv.y
                 + (h2f(hh.z) + h2f(hl.z)) * wv.z
                 + (h2f(hh.w) + h2f(hl.w)) * wv.w;
        }
        if (j < 40) out[(size_t)b * 40 + j] = acc + clsb[j];
        else        out[10240 + (size_t)b * 2 + (j - 40)] = acc + bbb[j - 40];
    }
    if (b == 0 && (j == 62 || j == 63)) out[10752 + (j - 62)] = 0.f;
}

extern "C" void kernel_launch(void* const* d_in, const int* in_sizes, int n_in,
                              void* d_out, int out_size, void* d_ws, size_t ws_size,
                              hipStream_t stream) {
    const float* proposals = (const float*)d_in[2];
    const float* Wih0 = (const float*)d_in[4];
    const float* Whh0 = (const float*)d_in[5];
    const float* bih0 = (const float*)d_in[6];
    const float* bhh0 = (const float*)d_in[7];
    const float* Wih1 = (const float*)d_in[8];
    const float* Whh1 = (const float*)d_in[9];
    const float* bih1 = (const float*)d_in[10];
    const float* bhh1 = (const float*)d_in[11];
    const float* clsW = (const float*)d_in[12];
    const float* clsb = (const float*)d_in[13];
    const float* bbW  = (const float*)d_in[14];
    const float* bbb  = (const float*)d_in[15];

    char* ws = (char*)d_ws;
    unsigned short* Ahi  = (unsigned short*)(ws + A_HI_OFF);
    unsigned short* xHi  = (unsigned short*)(ws + X_HI_OFF);
    unsigned short* xLo  = (unsigned short*)(ws + X_LO_OFF);
    unsigned short* hHi0 = (unsigned short*)(ws + HHI0_OFF);
    unsigned short* hHi1 = (unsigned short*)(ws + HHI1_OFF);
    unsigned short* hLo1 = (unsigned short*)(ws + HLO1_OFF);
    float4* b0pk = (float4*)(ws + B0PK_OFF);
    float4* b1pk = (float4*)(ws + B1PK_OFF);
    int*    arr  = (int*)(ws + ARR_OFF);

    hipMemsetAsync(arr, 0, ARR_BYTES, stream);

    pack_w<<<(int)A_FRAGS, 64, 0, stream>>>(Wih0, Whh0, Wih1, Whh1, Ahi);
    prep_x<<<200, 256, 0, stream>>>(proposals, xHi, xLo);
    pack_bias<<<1, 512, 0, stream>>>(bih0, bhh0, bih1, bhh1, b0pk, b1pk);

    lstm_scan<<<256, 512, 0, stream>>>(Ahi, xHi, xLo,
                                       hHi0, hHi1, hLo1,
                                       b0pk, b1pk, arr);

    heads<<<256, 64, 0, stream>>>(hHi1, hLo1, (const float4*)clsW, clsb,
                                  (const float4*)bbW, bbb, (float*)d_out);
}

// Round 13
// 1546.967 us; speedup vs baseline: 1.5359x; 1.0499x over previous
//
#include <hip/hip_runtime.h>
#include <math.h>

#define T_ALL 200
#define ROWB  1040                 // 1024 B h-row + 16 B pad (16B-aligned)
#define QUAD  (32 * ROWB)          // 33,280 B per h quadrant

typedef __attribute__((ext_vector_type(8)))  _Float16 v8h;
typedef __attribute__((ext_vector_type(16))) float v16f;

typedef __attribute__((address_space(1))) const unsigned int g_u32;
typedef __attribute__((address_space(3))) unsigned int l_u32;

// device-coherent global->LDS: aux=16 (sc1) reads the L3 coherence point,
// bypassing the possibly-stale local L2 (proven in prior sessions).
__device__ __forceinline__ void gl2lds16_coh(const void* g, void* l) {
    __builtin_amdgcn_global_load_lds((g_u32*)g, (l_u32*)l, 16, 0, 16);
}

// fp16 helpers (hardware v_cvt, round-to-nearest-even)
__device__ __forceinline__ unsigned short f2h(float f) {
    _Float16 h = (_Float16)f;
    return *(unsigned short*)&h;
}
__device__ __forceinline__ float h2f(unsigned short s) {
    _Float16 h = *(_Float16*)&s;
    return (float)h;
}
// hardware-exp transcendentals (v_exp_f32): ~1e-7 error, saturation-safe
__device__ __forceinline__ float sigf(float x)  { return 1.0f / (1.0f + __expf(-x)); }
__device__ __forceinline__ float tanhf_hw(float x) {
    return 1.0f - 2.0f / (__expf(2.0f * x) + 1.0f);   // e=inf -> 1; e=0 -> -1
}

// ---- ws layout (bytes; unchanged -- Alo/hLo0 regions now unused) ----
#define A_FRAGS   6656ULL
#define A_HI_OFF  0ULL
#define A_LO_OFF  (A_FRAGS * 1024ULL)
#define X_HI_OFF  (2ULL * A_FRAGS * 1024ULL)
#define X_BYTES   (200ULL * 256 * 128 * 2)
#define X_LO_OFF  (X_HI_OFF + X_BYTES)
#define H_BYTES   (2ULL * 256 * 512 * 2)
#define HHI0_OFF  (X_LO_OFF + X_BYTES)
#define HLO0_OFF  (HHI0_OFF + H_BYTES)
#define HHI1_OFF  (HLO0_OFF + H_BYTES)
#define HLO1_OFF  (HHI1_OFF + H_BYTES)
#define B0PK_OFF  (HLO1_OFF + H_BYTES)
#define B1PK_OFF  (B0PK_OFF + 8192ULL)
#define ARR_OFF   (B1PK_OFF + 8192ULL)
#define ARR_BYTES (256ULL * 64)              // one 64B-spread arrive slot per block

// Pack W rows into MFMA 32x32x16 A-fragment order, SINGLE fp16 plane.
__global__ __launch_bounds__(64) void pack_w(
    const float* __restrict__ Wih0, const float* __restrict__ Whh0,
    const float* __restrict__ Wih1, const float* __restrict__ Whh1,
    unsigned short* __restrict__ Ahi)
{
    const int fi = blockIdx.x, lane = threadIdx.x;
    const float* W; int K, hg, c;
    if (fi < 512)       { W = Wih0; K = 128; hg = fi >> 3;          c = fi & 7;          }
    else if (fi < 2560) { W = Whh0; K = 512; hg = (fi - 512) >> 5;  c = (fi - 512) & 31; }
    else if (fi < 4608) { W = Wih1; K = 512; hg = (fi - 2560) >> 5; c = (fi - 2560) & 31;}
    else                { W = Whh1; K = 512; hg = (fi - 4608) >> 5; c = (fi - 4608) & 31;}
    const int m = lane & 31, half = lane >> 5;
    const int q = m & 3, hl = m >> 2;
    const int r = q * 512 + hg * 8 + hl;
    const int k0 = c * 16 + half * 8;
    const float* src = W + (size_t)r * K + k0;
    unsigned short* dh = Ahi + (size_t)fi * 512 + lane * 8;
    #pragma unroll
    for (int j = 0; j < 8; ++j)
        dh[j] = f2h(src[j]);
}

// proposals [b][t][c] fp32 -> xHi/xLo [t][b][c] fp16 hi + fp16 residual
__global__ __launch_bounds__(256) void prep_x(const float* __restrict__ prop,
                                              unsigned short* __restrict__ xHi,
                                              unsigned short* __restrict__ xLo)
{
    const int t = blockIdx.x, b = threadIdx.x;
    const float* src = prop + ((size_t)b * 200 + t) * 128;
    unsigned short* dh = xHi + ((size_t)t * 256 + b) * 128;
    unsigned short* dl = xLo + ((size_t)t * 256 + b) * 128;
    #pragma unroll 4
    for (int c = 0; c < 128; ++c) {
        const float f = src[c];
        const unsigned short h = f2h(f);
        dh[c] = h;
        dl[c] = f2h(f - h2f(h));
    }
}

// bias packs: bpk[hid] = float4 over gates (i,f,g,o)
__global__ __launch_bounds__(512) void pack_bias(
    const float* __restrict__ bih0, const float* __restrict__ bhh0,
    const float* __restrict__ bih1, const float* __restrict__ bhh1,
    float4* __restrict__ b0, float4* __restrict__ b1)
{
    const int hid = threadIdx.x;
    float4 u, v;
    u.x = bih0[hid] + bhh0[hid];
    u.y = bih0[512 + hid] + bhh0[512 + hid];
    u.z = bih0[1024 + hid] + bhh0[1024 + hid];
    u.w = bih0[1536 + hid] + bhh0[1536 + hid];
    v.x = bih1[hid] + bhh1[hid];
    v.y = bih1[512 + hid] + bhh1[512 + hid];
    v.z = bih1[1024 + hid] + bhh1[1024 + hid];
    v.w = bih1[1536 + hid] + bhh1[1536 + hid];
    b0[hid] = u; b1[hid] = v;
}

// PERSISTENT fused scan -- R12 structure (verified 1624us: fp16 single-plane
// weights + single-plane h, single accumulator, 2-row prefetch, R5 tail).
// This round: LDS WEIGHT CACHE.  The h-plane halving freed 66KB of LDS
// (1 block/CU regardless), so each recurrent wave parks 12 of its 32 weight
// rows in LDS (6 waves x 12KB = 72KB; total 160,768B <= 160KB), loaded ONCE
// in the prologue.  Per-step weight L2 stream drops 208 -> 124 KB/block
// (6.7 -> 4.0 MB/XCD/step against the measured ~4.3TB/s per-XCD L2 ceiling
// that bounds region A).  Rows c=0,1 register-prefetched (R9), c=2..13 from
// LDS, c=14..31 from L2.  Math bit-identical (same fp16 weights, different
// storage): absmax must stay exactly 7.629395e-06.  No barrier changes --
// each wave reads only its own cached rows (in-wave lgkmcnt ordering).
__global__ __launch_bounds__(512) void lstm_scan(
    const unsigned short* __restrict__ Ahi,
    const unsigned short* __restrict__ xHi, const unsigned short* __restrict__ xLo,
    unsigned short* __restrict__ hHi0,
    unsigned short* __restrict__ hHi1, unsigned short* __restrict__ hLo1,
    const float4* __restrict__ b0pk, const float4* __restrict__ b1pk,
    int* __restrict__ arr)
{
    __shared__ __align__(16) unsigned char dbuf[2 * QUAD];       //  66,560 B
    __shared__ float xch[2][2][32][32];                          //  16,384 B
    __shared__ __align__(16) unsigned short hst[2][2][32][16];   //   4,096 B
    __shared__ __align__(16) unsigned char wcache[6][12 * 1024]; //  73,728 B

    const int tid  = threadIdx.x;
    const int wv   = tid >> 6, lane = tid & 63;
    const int mv   = wv >> 1, hgi = wv & 1;
    const int f    = blockIdx.x;                   // 0..255
    const int hgp  = (f & 7) * 4 + ((f >> 3) & 3); // 4 hg-pairs per XCD
    const int bt   = f >> 5;                       // batch tile 0..7 = sync group
    const int hg   = hgp * 2 + hgi;                // hid group 0..63
    const int ml   = lane & 31, half = lane >> 5;
    const int gslot = f & 31;                      // our slot within the group
    const int widx = wv - 2;                       // wcache index (recurrent waves)

    int fbase;
    if (mv == 0)      fbase = hg * 8;
    else if (mv == 1) fbase = 512 + hg * 32;
    else if (mv == 2) fbase = 2560 + hg * 32;
    else              fbase = 4608 + hg * 32;

    float4 bs[4];
    #pragma unroll
    for (int rq = 0; rq < 4; ++rq) {
        const int hid = hg * 8 + 2 * rq + half;
        bs[rq] = (mv == 1) ? b0pk[hid] : (mv == 3) ? b1pk[hid]
                                       : make_float4(0.f, 0.f, 0.f, 0.f);
    }
    float creg[4] = {0.f, 0.f, 0.f, 0.f};

    // ---- prologue: park weight rows c=2..13 in LDS (once; own-wave only) ----
    if (mv >= 1) {
        #pragma unroll
        for (int r = 0; r < 12; ++r) {
            const v8h w = *(const v8h*)(Ahi + ((size_t)(fbase + 2 + r)) * 512 + lane * 8);
            *(v8h*)(&wcache[widx][r * 1024 + lane * 16]) = w;
        }
    }

    for (int t = 0; t <= T_ALL; ++t) {
        const int rs0 = (t + 1) & 1;   // h0[t-1] slot
        const int rs1 = t & 1;         // h1[t-2] slot
        const unsigned short* srcq[2] = {
            hHi0 + ((size_t)rs0 * 256 + bt * 32) * 512,
            hHi1 + ((size_t)rs1 * 256 + bt * 32) * 512 };

        // ---- staging burst: 64 rows (2 hi quadrants x 32 batches) ----
        #pragma unroll
        for (int j = 0; j < 8; ++j) {
            const int row = wv * 8 + j;
            const int q = row >> 5, r = row & 31;
            gl2lds16_coh(srcq[q] + (size_t)r * 512 + lane * 8,
                         &dbuf[q * QUAD + r * ROWB]);
        }

        // recurrent waves: prefetch weight rows c=0,1 (drain with staging)
        v8h pf0h, pf1h;
        if (mv >= 1) {
            pf0h = *(const v8h*)(Ahi + ((size_t)(fbase + 0)) * 512 + lane * 8);
            pf1h = *(const v8h*)(Ahi + ((size_t)(fbase + 1)) * 512 + lane * 8);
        }

        v16f A0;
        #pragma unroll
        for (int i = 0; i < 16; ++i) A0[i] = 0.f;

        // mv0: x-matvec (plain loads, independent of dbuf) before the drain
        if (mv == 0 && t < T_ALL) {
            const unsigned short* xh = xHi + ((size_t)t * 256 + bt * 32 + ml) * 128 + half * 8;
            const unsigned short* xl = xLo + ((size_t)t * 256 + bt * 32 + ml) * 128 + half * 8;
            #pragma unroll
            for (int c = 0; c < 8; ++c) {
                const v8h ah = *(const v8h*)(Ahi + ((size_t)(fbase + c)) * 512 + lane * 8);
                const v8h bh = *(const v8h*)(xh + c * 16);
                const v8h bl = *(const v8h*)(xl + c * 16);
                A0 = __builtin_amdgcn_mfma_f32_32x32x16_f16(ah, bh, A0, 0, 0, 0);
                A0 = __builtin_amdgcn_mfma_f32_32x32x16_f16(ah, bl, A0, 0, 0, 0);
            }
            #pragma unroll
            for (int r = 0; r < 16; ++r)
                xch[0][hgi][(r & 3) + 8 * (r >> 2) + 4 * half][ml] = A0[r];
            #pragma unroll
            for (int i = 0; i < 16; ++i) A0[i] = 0.f;
        }
        __syncthreads();   // barrier1: staging + prefetch drained, xch[0] published

        // wave 0 idle window: bounded pre-poll (byte-identical to R5/R9/R11)
        bool preOK = false;
        if (wv == 0 && t < T_ALL) {
            #pragma unroll 1
            for (int it = 0; it < 4 && !preOK; ++it) {
                int v = 0x7FFFFFFF;
                if (lane < 32)
                    v = __hip_atomic_load(arr + ((size_t)bt * 32 + lane) * 16,
                                          __ATOMIC_RELAXED, __HIP_MEMORY_SCOPE_AGENT);
                preOK = __all(lane >= 32 || lane == gslot || v >= t + 1);
                if (!preOK) __builtin_amdgcn_s_sleep(1);
            }
        }

        // ---- recurrent matvecs from LDS (h0-hi for mv1/mv2, h1-hi for mv3) ----
        const bool a12 = (mv == 1) ? (t >= 1 && t < T_ALL)
                       : (mv == 2) ? (t >= 1) : false;
        const bool a3  = (mv == 3) && (t >= 2);
        if (a12 || a3) {
            const unsigned char* qhi = dbuf + (mv == 3 ? 1 : 0) * QUAD;
            // c = 0,1 peeled: weights already in registers (prefetched)
            {
                const v8h bh0 = *(const v8h*)(qhi + ml * ROWB + 0 * 32 + half * 16);
                A0 = __builtin_amdgcn_mfma_f32_32x32x16_f16(pf0h, bh0, A0, 0, 0, 0);
                const v8h bh1 = *(const v8h*)(qhi + ml * ROWB + 1 * 32 + half * 16);
                A0 = __builtin_amdgcn_mfma_f32_32x32x16_f16(pf1h, bh1, A0, 0, 0, 0);
            }
            // c = 2..13: weights from the LDS cache (no L2 traffic)
            #pragma unroll 6
            for (int c = 2; c < 14; ++c) {
                const v8h ah = *(const v8h*)(&wcache[widx][(c - 2) * 1024 + lane * 16]);
                const v8h bh = *(const v8h*)(qhi + ml * ROWB + c * 32 + half * 16);
                A0 = __builtin_amdgcn_mfma_f32_32x32x16_f16(ah, bh, A0, 0, 0, 0);
            }
            // c = 14..31: weights streamed from L2
            #pragma unroll 6
            for (int c = 14; c < 32; ++c) {
                const v8h ah = *(const v8h*)(Ahi + ((size_t)(fbase + c)) * 512 + lane * 8);
                const v8h bh = *(const v8h*)(qhi + ml * ROWB + c * 32 + half * 16);
                A0 = __builtin_amdgcn_mfma_f32_32x32x16_f16(ah, bh, A0, 0, 0, 0);
            }
        }

        // mv1: full epilogue now (xch[0] already published); h0 hi-plane only
        if (mv == 1 && t < T_ALL) {
            #pragma unroll
            for (int rq = 0; rq < 4; ++rq) {
                const int hl = 2 * rq + half;
                float a[4];
                #pragma unroll
                for (int j = 0; j < 4; ++j)
                    a[j] = A0[rq * 4 + j]
                         + xch[0][hgi][j + 8 * rq + 4 * half][ml]
                         + ((const float*)&bs[rq])[j];
                const float ig = sigf(a[0]), fg = sigf(a[1]);
                const float gg = tanhf_hw(a[2]), og = sigf(a[3]);
                creg[rq] = fg * creg[rq] + ig * gg;
                const float h = og * tanhf_hw(creg[rq]);
                hst[0][0][ml][hgi * 8 + hl] = f2h(h);
            }
        }
        if (mv == 2 && t >= 1) {
            #pragma unroll
            for (int r = 0; r < 16; ++r)
                xch[1][hgi][(r & 3) + 8 * (r >> 2) + 4 * half][ml] = A0[r];
        }
        __syncthreads();   // barrier2: xch[1] + hst[0] published

        // EARLY h0 store (threads 0..127; hi plane only, R0 discipline)
        if (tid < 128 && t < T_ALL) {
            const int bl = (tid >> 2) & 31, hq = tid & 3;
            const unsigned long long val =
                *(const unsigned long long*)&hst[0][0][bl][hq * 4];
            unsigned long long* dst = (unsigned long long*)
                (hHi0 + ((size_t)(t & 1) * 256 + bt * 32 + bl) * 512 + hgp * 16 + hq * 4);
            __hip_atomic_store(dst, val, __ATOMIC_RELAXED, __HIP_MEMORY_SCOPE_AGENT);
        }

        // mv3 epilogue: layer-1 update h1[t-1] (hi + lo; lo feeds heads only)
        if (mv == 3 && t >= 1) {
            #pragma unroll
            for (int rq = 0; rq < 4; ++rq) {
                const int hl = 2 * rq + half;
                float a[4];
                #pragma unroll
                for (int j = 0; j < 4; ++j)
                    a[j] = A0[rq * 4 + j]
                         + xch[1][hgi][j + 8 * rq + 4 * half][ml]
                         + ((const float*)&bs[rq])[j];
                const float ig = sigf(a[0]), fg = sigf(a[1]);
                const float gg = tanhf_hw(a[2]), og = sigf(a[3]);
                creg[rq] = fg * creg[rq] + ig * gg;
                const float h = og * tanhf_hw(creg[rq]);
                const unsigned short hh = f2h(h);
                hst[1][0][ml][hgi * 8 + hl] = hh;
                hst[1][1][ml][hgi * 8 + hl] = f2h(h - h2f(hh));
            }
        }
        __syncthreads();   // barrier3: hst[1] published

        // h1 cooperative store (threads 256..511; hi+lo, R0 layout)
        if (tid >= 256 && t >= 1) {
            const int plane = (tid >> 7) & 1;
            const int bl = (tid >> 2) & 31, hq = tid & 3;
            const unsigned long long val =
                *(const unsigned long long*)&hst[1][plane][bl][hq * 4];
            unsigned short* basep = plane ? hLo1 : hHi1;
            unsigned long long* dst = (unsigned long long*)
                (basep + ((size_t)((t + 1) & 1) * 256 + bt * 32 + bl) * 512 + hgp * 16 + hq * 4);
            __hip_atomic_store(dst, val, __ATOMIC_RELAXED, __HIP_MEMORY_SCOPE_AGENT);
        }

        if (t < T_ALL) {
            __threadfence_block();       // drain h stores (vmcnt)
            __syncthreads();
            if (tid == 0)
                __hip_atomic_store(arr + (size_t)f * 16, t + 1,
                                   __ATOMIC_RELAXED, __HIP_MEMORY_SCOPE_AGENT);
            // wave 0 polls the 32 arrive slots -- skipped if pre-poll hit
            if (wv == 0 && !preOK) {
                int v = 0x7FFFFFFF;
                do {
                    if (lane < 32)
                        v = __hip_atomic_load(arr + ((size_t)bt * 32 + lane) * 16,
                                              __ATOMIC_RELAXED, __HIP_MEMORY_SCOPE_AGENT);
                    if (__all(lane >= 32 || v >= t + 1)) break;
                    __builtin_amdgcn_s_sleep(1);
                } while (true);
            }
            __syncthreads();
        }
    }
}

// heads: base_feat = h1[:,199] (slot 1, fp16 hi+lo reconstruct) -> cls/bbox
__global__ __launch_bounds__(64) void heads(
    const unsigned short* __restrict__ hHi1, const unsigned short* __restrict__ hLo1,
    const float4* __restrict__ clsW, const float* __restrict__ clsb,
    const float4* __restrict__ bbW, const float* __restrict__ bbb,
    float* __restrict__ out)
{
    const int b = blockIdx.x, j = threadIdx.x;
    const size_t off = (size_t)(256 + b) * 512;   // slot 1
    if (j < 42) {
        const float4* w = (j < 40) ? (clsW + (size_t)j * 128) : (bbW + (size_t)(j - 40) * 128);
        float acc = 0.f;
        #pragma unroll 4
        for (int k4 = 0; k4 < 128; ++k4) {
            const ushort4 hh = *(const ushort4*)(hHi1 + off + k4 * 4);
            const ushort4 hl = *(const ushort4*)(hLo1 + off + k4 * 4);
            const float4 wv = w[k4];
            acc += (h2f(hh.x) + h2f(hl.x)) * wv.x
                 + (h2f(hh.y) + h2f(hl.y)) * wv.y
                 + (h2f(hh.z) + h2f(hl.z)) * wv.z
                 + (h2f(hh.w) + h2f(hl.w)) * wv.w;
        }
        if (j < 40) out[(size_t)b * 40 + j] = acc + clsb[j];
        else        out[10240 + (size_t)b * 2 + (j - 40)] = acc + bbb[j - 40];
    }
    if (b == 0 && (j == 62 || j == 63)) out[10752 + (j - 62)] = 0.f;
}

extern "C" void kernel_launch(void* const* d_in, const int* in_sizes, int n_in,
                              void* d_out, int out_size, void* d_ws, size_t ws_size,
                              hipStream_t stream) {
    const float* proposals = (const float*)d_in[2];
    const float* Wih0 = (const float*)d_in[4];
    const float* Whh0 = (const float*)d_in[5];
    const float* bih0 = (const float*)d_in[6];
    const float* bhh0 = (const float*)d_in[7];
    const float* Wih1 = (const float*)d_in[8];
    const float* Whh1 = (const float*)d_in[9];
    const float* bih1 = (const float*)d_in[10];
    const float* bhh1 = (const float*)d_in[11];
    const float* clsW = (const float*)d_in[12];
    const float* clsb = (const float*)d_in[13];
    const float* bbW  = (const float*)d_in[14];
    const float* bbb  = (const float*)d_in[15];

    char* ws = (char*)d_ws;
    unsigned short* Ahi  = (unsigned short*)(ws + A_HI_OFF);
    unsigned short* xHi  = (unsigned short*)(ws + X_HI_OFF);
    unsigned short* xLo  = (unsigned short*)(ws + X_LO_OFF);
    unsigned short* hHi0 = (unsigned short*)(ws + HHI0_OFF);
    unsigned short* hHi1 = (unsigned short*)(ws + HHI1_OFF);
    unsigned short* hLo1 = (unsigned short*)(ws + HLO1_OFF);
    float4* b0pk = (float4*)(ws + B0PK_OFF);
    float4* b1pk = (float4*)(ws + B1PK_OFF);
    int*    arr  = (int*)(ws + ARR_OFF);

    hipMemsetAsync(arr, 0, ARR_BYTES, stream);

    pack_w<<<(int)A_FRAGS, 64, 0, stream>>>(Wih0, Whh0, Wih1, Whh1, Ahi);
    prep_x<<<200, 256, 0, stream>>>(proposals, xHi, xLo);
    pack_bias<<<1, 512, 0, stream>>>(bih0, bhh0, bih1, bhh1, b0pk, b1pk);

    lstm_scan<<<256, 512, 0, stream>>>(Ahi, xHi, xLo,
                                       hHi0, hHi1, hLo1,
                                       b0pk, b1pk, arr);

    heads<<<256, 64, 0, stream>>>(hHi1, hLo1, (const float4*)clsW, clsb,
                                  (const float4*)bbW, bbb, (float*)d_out);
}